// Round 10
// baseline (6410.107 us; speedup 1.0000x reference)
//
#include <hip/hip_runtime.h>
#include <cstdint>
#include <cstddef>

// (B,H,S,Dh) = (2, 8, 2048, 64), all float32 in/out.
#define BB 2
#define HH 8
#define SS 2048
#define DD 64
#define NST 32                 // 64-kv strips per row
#define QW 4                   // q rows per WG (shared by all 8 heads)
#define NROWS (BB * HH * SS)

typedef float f32x4 __attribute__((ext_vector_type(4)));
using u32 = unsigned int;
using u8  = unsigned char;

// Barrier draining ONLY the LDS queue — __syncthreads also drains vmcnt(0),
// which would serialize the in-flight HBM bias prefetch (m97 drain).
__device__ __forceinline__ void lds_barrier() {
  __builtin_amdgcn_sched_barrier(0);
  asm volatile("s_waitcnt lgkmcnt(0)" ::: "memory");
  __builtin_amdgcn_s_barrier();
  __builtin_amdgcn_sched_barrier(0);
}

// ---------------- K_mask: canonicalize mask -> u8[B*S] ---------------------
__global__ __launch_bounds__(256) void mask_canon(
    const void* __restrict__ maskg, u8* __restrict__ mc)
{
  __shared__ int sf, su;
  const int t = (int)threadIdx.x;
  if (t == 0) { sf = 0; su = 0; }
  __syncthreads();
  const u32* mw = (const u32*)maskg;
  int f = 0, u = 0;
  for (int i = t; i < 1024; i += 256) {   // 4KB scan: valid for all encodings
    u32 w = mw[i];
    if (w == 0x3F800000u) f = 1;
    if (w > 1u && w != 0x3F800000u) u = 1;
  }
  if (f) sf = 1;
  if (u) su = 1;
  __syncthreads();
  const int mode = sf ? 2 : (su ? 1 : 0);
  for (int i = t; i < BB * SS; i += 256) {
    u8 m;
    if (mode == 2)      m = (((const float*)maskg)[i] != 0.0f) ? 1 : 0;
    else if (mode == 1) m = (((const u8*)maskg)[i] != 0) ? 1 : 0;
    else                m = (((const int*)maskg)[i] != 0) ? 1 : 0;
    mc[i] = m;
  }
}

// ---------------- K_t: k[bh][kv][d] -> ktw[bh][st][d4][kvl][4] (f32) -------
// Lane reads 256B-contiguous rows; writes 64B runs (one-off 8.4MB, ~5us).
__global__ __launch_bounds__(256) void ktrans_kernel(
    const float* __restrict__ k, float* __restrict__ ktw)
{
  const int t   = (int)(blockIdx.x * 256 + threadIdx.x);  // < 524288
  const int d4  = t & 15;
  const int row = t >> 4;            // bh*2048 + kv
  const int bh  = row >> 11;
  const int kv  = row & 2047;
  const int st  = kv >> 6;
  const int kvl = kv & 63;
  const float4 v = *(const float4*)(k + (size_t)row * DD + d4 * 4);
  *(float4*)(ktw + ((((size_t)bh * NST + st) * 16 + d4) * 256) + kvl * 4) = v;
}

// ---------------- Fused: scores + bias + exp + rowsum + normalize ----------
// WG = 512 thr = 8 waves = 8 heads, (b, 4 q-rows), FULL 2048 kv.
// Per strip (64 kv): lane owns kv=lane. k^T float4 loads (coalesced),
// q via LDS b128 broadcast, bias via dbuf LDS transpose (2-way banks).
// Rowsums accumulate in registers -> wave-local reduce -> in-kernel
// normalize pass over the wave's own just-written rows (L2-hot). f32 only.
__global__ __launch_bounds__(512, 4) void fused_kernel(
    const float* __restrict__ qg, const float* __restrict__ ktw,
    const float* __restrict__ scaleg, const u8* __restrict__ maskc,
    const float* __restrict__ biasg, float* __restrict__ outg)
{
  __shared__ float q_lds[HH][QW][DD];       // 8 KB
  __shared__ float b_lds[2][HH][QW][64];    // 16 KB
  __shared__ u8    m_lds[SS];               // 2 KB

  const int t    = (int)threadIdx.x;
  const int wid  = t >> 6;        // wave = head
  const int lane = t & 63;

  // chunked XCD swizzle: each XCD's 128 WGs share one b's k^T (4.2MB -> L2)
  const int bid = (int)blockIdx.x;
  const int wg  = (bid & 7) * 128 + (bid >> 3);   // bijective on 1024
  const int b   = wg >> 9;
  const int q0  = (wg & 511) * QW;

  // ---- q stage: one float4 per thread ----
  {
    const int h = t >> 6, r = (t >> 4) & 3, d4 = t & 15;
    const float4 v = *(const float4*)(
        qg + ((size_t)(b * HH + h) * SS + q0 + r) * DD + d4 * 4);
    *(float4*)&q_lds[h][r][d4 * 4] = v;
  }
  // ---- mask stage: u32 per thread ----
  ((u32*)m_lds)[t] = ((const u32*)(maskc + b * SS))[t];

  // ---- bias staging roles: thread t <-> (r = t>>7, kv = (t>>1)&63, h4 = t&1)
  const int h4  = t & 1;
  const int kvs = (t >> 1) & 63;
  const int rs_ = t >> 7;
  const float* bsrc = biasg +
      (((size_t)(b * SS + q0 + rs_)) * SS + kvs) * HH + h4 * 4;
  float4 pr;

#define LOADB(c) pr = *(const float4*)(bsrc + (size_t)(c) * (64 * HH))
#define STAGEB(c) do {                                                   \
    float* _d = &b_lds[(c) & 1][h4 * 4][rs_][kvs];                       \
    _d[0]            = pr.x;                                             \
    _d[QW * 64]      = pr.y;                                             \
    _d[2 * QW * 64]  = pr.z;                                             \
    _d[3 * QW * 64]  = pr.w;                                             \
  } while (0)

  LOADB(0);
  STAGEB(0);
  LOADB(1);
  __syncthreads();   // q, mask, bias buf0 visible (single full drain)

  const float inv_scale = 1.0f / scaleg[0];
  const float* ktb = ktw + (size_t)(b * HH + wid) * (NST * 16 * 256);
  float* ob = outg + ((size_t)(b * HH + wid) * SS + q0) * SS;

  float rsum0 = 0.f, rsum1 = 0.f, rsum2 = 0.f, rsum3 = 0.f;

  for (int c = 0; c < NST; ++c) {
    float a0 = 0.f, a1 = 0.f, a2 = 0.f, a3 = 0.f;
    const float* kp = ktb + (size_t)c * 4096 + lane * 4;
#pragma unroll
    for (int d4 = 0; d4 < 16; ++d4) {
      const float4 kv4 = *(const float4*)(kp + d4 * 256);
      const float4 qa  = *(const float4*)&q_lds[wid][0][d4 * 4];
      const float4 qb  = *(const float4*)&q_lds[wid][1][d4 * 4];
      const float4 qc  = *(const float4*)&q_lds[wid][2][d4 * 4];
      const float4 qd  = *(const float4*)&q_lds[wid][3][d4 * 4];
      a0 = fmaf(kv4.x, qa.x, a0); a0 = fmaf(kv4.y, qa.y, a0);
      a0 = fmaf(kv4.z, qa.z, a0); a0 = fmaf(kv4.w, qa.w, a0);
      a1 = fmaf(kv4.x, qb.x, a1); a1 = fmaf(kv4.y, qb.y, a1);
      a1 = fmaf(kv4.z, qb.z, a1); a1 = fmaf(kv4.w, qb.w, a1);
      a2 = fmaf(kv4.x, qc.x, a2); a2 = fmaf(kv4.y, qc.y, a2);
      a2 = fmaf(kv4.z, qc.z, a2); a2 = fmaf(kv4.w, qc.w, a2);
      a3 = fmaf(kv4.x, qd.x, a3); a3 = fmaf(kv4.y, qd.y, a3);
      a3 = fmaf(kv4.z, qd.z, a3); a3 = fmaf(kv4.w, qd.w, a3);
    }

    if (c + 1 < NST) STAGEB(c + 1);   // regs loaded one strip ago
    if (c + 2 < NST) LOADB(c + 2);    // HBM prefetch, stays in flight

    // epilogue: bias + exp (+ mask), store unnormalized, accumulate rowsum
    const int kvg = c * 64 + lane;
    const float mz = m_lds[kvg] ? 0.0f : 1.0f;
    const int cb = c & 1;
    {
      const float w0 = mz * __expf(fmaf(a0, inv_scale, b_lds[cb][wid][0][lane]));
      const float w1 = mz * __expf(fmaf(a1, inv_scale, b_lds[cb][wid][1][lane]));
      const float w2 = mz * __expf(fmaf(a2, inv_scale, b_lds[cb][wid][2][lane]));
      const float w3 = mz * __expf(fmaf(a3, inv_scale, b_lds[cb][wid][3][lane]));
      rsum0 += w0; rsum1 += w1; rsum2 += w2; rsum3 += w3;
      ob[(size_t)0 * SS + kvg] = w0;
      ob[(size_t)1 * SS + kvg] = w1;
      ob[(size_t)2 * SS + kvg] = w2;
      ob[(size_t)3 * SS + kvg] = w3;
    }
    lds_barrier();   // buf[(c+1)&1] staged; buf[c&1] reads retired
  }
#undef LOADB
#undef STAGEB

  // ---- wave-local rowsum reduce (64 lanes) ----
#pragma unroll
  for (int off = 1; off < 64; off <<= 1) {
    rsum0 += __shfl_xor(rsum0, off, 64);
    rsum1 += __shfl_xor(rsum1, off, 64);
    rsum2 += __shfl_xor(rsum2, off, 64);
    rsum3 += __shfl_xor(rsum3, off, 64);
  }
  const float i0 = (rsum0 > 0.f) ? (1.0f / rsum0) : 0.f;
  const float i1 = (rsum1 > 0.f) ? (1.0f / rsum1) : 0.f;
  const float i2 = (rsum2 > 0.f) ? (1.0f / rsum2) : 0.f;
  const float i3 = (rsum3 > 0.f) ? (1.0f / rsum3) : 0.f;

  // ---- in-kernel normalize: re-read own rows (L2-hot), scale, store ----
#pragma unroll
  for (int j = 0; j < 8; ++j) {
    const size_t o = (size_t)(j * 64 + lane) * 4;
    f32x4 v0 = *(f32x4*)(ob + 0 * SS + o);
    f32x4 v1 = *(f32x4*)(ob + 1 * SS + o);
    f32x4 v2 = *(f32x4*)(ob + 2 * SS + o);
    f32x4 v3 = *(f32x4*)(ob + 3 * SS + o);
    v0 *= i0; v1 *= i1; v2 *= i2; v3 *= i3;
    *(f32x4*)(ob + 0 * SS + o) = v0;
    *(f32x4*)(ob + 1 * SS + o) = v1;
    *(f32x4*)(ob + 2 * SS + o) = v2;
    *(f32x4*)(ob + 3 * SS + o) = v3;
  }
}

extern "C" void kernel_launch(void* const* d_in, const int* in_sizes, int n_in,
                              void* d_out, int out_size, void* d_ws, size_t ws_size,
                              hipStream_t stream) {
  const float* qg = (const float*)d_in[0];
  const float* kg = (const float*)d_in[1];
  const float* sc = (const float*)d_in[2];
  const void*  mk = d_in[3];
  const float* bg = (const float*)d_in[4];
  float* out = (float*)d_out;

  // workspace: ktw 8.4MB | maskc 4KB
  float* ktw = (float*)d_ws;
  u8*    mcw = (u8*)(ktw + (size_t)NROWS * DD);

  mask_canon<<<dim3(1), dim3(256), 0, stream>>>(mk, mcw);
  ktrans_kernel<<<dim3((NROWS * (DD / 4)) / 256), dim3(256), 0, stream>>>(kg, ktw);

  fused_kernel<<<dim3(BB * (SS / QW)), dim3(512), 0, stream>>>(
      qg, ktw, sc, mcw, bg, out);
}

// Round 11
// 286.244 us; speedup vs baseline: 22.3939x; 22.3939x over previous
//
#include <hip/hip_runtime.h>
#include <cstdint>
#include <cstddef>

// (B,H,S,Dh) = (2, 8, 2048, 64), all float32 in/out.
#define BB 2
#define HH 8
#define SS 2048
#define DD 64
#define KP 128                 // bf16 hi|lo concatenated along k-dim
#define QT 32                  // q rows per WG
#define KSPLIT 8
#define KRANGE (SS / KSPLIT)   // 256 kv per WG
#define CKV 32                 // kv per chunk (two MFMA tiles)
#define NCH (KRANGE / CKV)     // 8 chunks
#define LROW 36                // LDS row stride in u32 (32 kv + 4 pad, 16B-aligned)
#define PLANE (QT * LROW)      // 1152 u32 per h-pair plane
#define BUFSTR (4 * PLANE)     // 4608 u32 per buffer (18.4 KB)
#define NROWS (BB * HH * SS)   // 32768 (b,h,row) triples

typedef short short8 __attribute__((ext_vector_type(8)));
typedef float f32x4  __attribute__((ext_vector_type(4)));
typedef unsigned int u32x4 __attribute__((ext_vector_type(4)));
using u16 = unsigned short;
using u32 = unsigned int;
using u8  = unsigned char;

__device__ inline u16 bf16_rne(float f) {
  u32 u = __builtin_bit_cast(u32, f);
  u32 r = (u + 0x7FFFu + ((u >> 16) & 1u)) >> 16;
  return (u16)r;
}
__device__ inline float bf16_to_f(u16 h) {
  u32 u = ((u32)h) << 16;
  return __builtin_bit_cast(float, u);
}
__device__ inline u32 pack_bf16(float a, float b) {
  return (u32)bf16_rne(a) | ((u32)bf16_rne(b) << 16);
}

// ---------------- K_mask: canonicalize mask -> u8[B*S] ---------------------
__global__ __launch_bounds__(256) void mask_canon(
    const void* __restrict__ maskg, u8* __restrict__ mc)
{
  __shared__ int sf, su;
  const int t = (int)threadIdx.x;
  if (t == 0) { sf = 0; su = 0; }
  __syncthreads();
  const u32* mw = (const u32*)maskg;
  int f = 0, u = 0;
  for (int i = t; i < 1024; i += 256) {   // 4KB scan: valid for all encodings
    u32 w = mw[i];
    if (w == 0x3F800000u) f = 1;
    if (w > 1u && w != 0x3F800000u) u = 1;
  }
  if (f) sf = 1;
  if (u) su = 1;
  __syncthreads();
  const int mode = sf ? 2 : (su ? 1 : 0);
  for (int i = t; i < BB * SS; i += 256) {
    u8 m;
    if (mode == 2)      m = (((const float*)maskg)[i] != 0.0f) ? 1 : 0;
    else if (mode == 1) m = (((const u8*)maskg)[i] != 0) ? 1 : 0;
    else                m = (((const int*)maskg)[i] != 0) ? 1 : 0;
    mc[i] = m;
  }
}

// ---------------- K0: f32 -> bf16 hi|lo (K=64 -> K=128) --------------------
__global__ __launch_bounds__(256) void convert_kernel(
    const float* __restrict__ q, const float* __restrict__ k,
    u16* __restrict__ qw, u16* __restrict__ kw)
{
  const int i   = (int)(blockIdx.x * 256 + threadIdx.x);  // float4 index
  const int row = i >> 4;
  const int c4  = (i & 15) << 2;

  const float4 qv = *(const float4*)(q + (size_t)i * 4);
  const float4 kv = *(const float4*)(k + (size_t)i * 4);

  u16 qh[4], ql[4], kh[4], kl[4];
  {
    const float qa[4] = {qv.x, qv.y, qv.z, qv.w};
    const float ka[4] = {kv.x, kv.y, kv.z, kv.w};
#pragma unroll
    for (int j = 0; j < 4; ++j) {
      qh[j] = bf16_rne(qa[j]);
      ql[j] = bf16_rne(qa[j] - bf16_to_f(qh[j]));
      kh[j] = bf16_rne(ka[j]);
      kl[j] = bf16_rne(ka[j] - bf16_to_f(kh[j]));
    }
  }

  uint2 qhi, qlo, khi, klo;
  qhi.x = (u32)qh[0] | ((u32)qh[1] << 16); qhi.y = (u32)qh[2] | ((u32)qh[3] << 16);
  qlo.x = (u32)ql[0] | ((u32)ql[1] << 16); qlo.y = (u32)ql[2] | ((u32)ql[3] << 16);
  khi.x = (u32)kh[0] | ((u32)kh[1] << 16); khi.y = (u32)kh[2] | ((u32)kh[3] << 16);
  klo.x = (u32)kl[0] | ((u32)kl[1] << 16); klo.y = (u32)kl[2] | ((u32)kl[3] << 16);

  const size_t base = (size_t)row * KP + c4;
  *(uint2*)(qw + base)      = qhi;
  *(uint2*)(qw + base + DD) = qlo;
  *(uint2*)(kw + base)      = khi;
  *(uint2*)(kw + base + DD) = klo;
}

// ---------------- K1: scores + bias + exp -> w' (unnormalized) -------------
// WG = 512 = 8 waves = 8 heads, same (b, q-tile 32, kv-range 256).
// SWAPPED MFMA: mfma(A=k, B=q) => lane owns q-row = l15(+16), kv run l4*4..+3
// -> float4 stores, u32x4 LDS bias reads. Bias dbuf in LDS (bf16-packed,
// 2 heads/u32, plane per h-pair). ONE plain __syncthreads per 32-kv chunk;
// no inline-asm fences (m141: order-pinning regresses). Bias prefetch issued
// EARLY in the chunk (dual prA/prB reg sets) so the barrier drain is cheap.
__global__ __launch_bounds__(512, 4) void score_kernel(
    const u16* __restrict__ qw, const u16* __restrict__ kw,
    const float* __restrict__ scaleg, const u8* __restrict__ maskc,
    const float* __restrict__ biasg, float* __restrict__ outg)
{
  __shared__ u32 s_b32[2 * BUFSTR];      // 36.9 KB
  __shared__ u32 s_mask32[KRANGE / 4];   // 256 mask bytes as u32

  const int t    = (int)threadIdx.x;
  const int wid  = t >> 6;        // wave = head
  const int lane = t & 63;
  const int l15  = lane & 15;
  const int l4   = lane >> 4;

  const int bid = (int)blockIdx.x;
  const int b   = bid / ((SS / QT) * KSPLIT);
  const int rem = bid % ((SS / QT) * KSPLIT);
  const int q0     = (rem / KSPLIT) * QT;
  const int ks     = rem % KSPLIT;
  const int kvbase = ks * KRANGE;

  if (t < KRANGE / 4)
    s_mask32[t] = *(const u32*)(maskc + b * SS + kvbase + t * 4);

  const float inv_scale = 1.0f / scaleg[0];
  const size_t bh = (size_t)(b * HH + wid);

  // ---- bias staging: thread t <-> (qr_s = t>>4, kv pair kv2 = (t&15)*2) ----
  // per chunk the thread loads 64B contiguous: {kv2,kv2+1} x heads 0..7.
  const int qr_s = t >> 4;
  const int kv2  = (t & 15) * 2;
  const float* bsrc = biasg +
      (((size_t)(b * SS + q0 + qr_s)) * SS + kvbase + kv2) * HH;
  float4 prA[4], prB[4];

#define LOADB(P, c) do {                                                  \
    const float4* _p = (const float4*)(bsrc + (size_t)(c) * (CKV * HH));  \
    P[0] = _p[0]; P[1] = _p[1]; P[2] = _p[2]; P[3] = _p[3];               \
  } while (0)

#define STAGEB(P, c) do {                                                 \
    u32* _d = &s_b32[((c) & 1) * BUFSTR + qr_s * LROW + kv2];             \
    _d[0]             = pack_bf16(P[0].x, P[0].y);                        \
    _d[PLANE]         = pack_bf16(P[0].z, P[0].w);                        \
    _d[2 * PLANE]     = pack_bf16(P[1].x, P[1].y);                        \
    _d[3 * PLANE]     = pack_bf16(P[1].z, P[1].w);                        \
    _d[1]             = pack_bf16(P[2].x, P[2].y);                        \
    _d[1 + PLANE]     = pack_bf16(P[2].z, P[2].w);                        \
    _d[1 + 2 * PLANE] = pack_bf16(P[3].x, P[3].y);                        \
    _d[1 + 3 * PLANE] = pack_bf16(P[3].z, P[3].w);                        \
  } while (0)

  // ---- k fragments (2 ni-tiles x 4 kf per chunk) ----
  const u16* kwb = kw + (bh * SS + kvbase + l15) * KP + (l4 << 3);
  short8 kfr[2][4];
#define LOADK(c) do {                                                     \
    _Pragma("unroll")                                                     \
    for (int _ni = 0; _ni < 2; ++_ni)                                     \
      _Pragma("unroll")                                                   \
      for (int _kf = 0; _kf < 4; ++_kf)                                   \
        kfr[_ni][_kf] = *(const short8*)(                                 \
            kwb + ((size_t)(c) * CKV + _ni * 16) * KP + _kf * 32);        \
  } while (0)

  // ---- prologue ----
  LOADB(prA, 0);

  short8 afr[2][4];
#pragma unroll
  for (int mi = 0; mi < 2; ++mi)
#pragma unroll
    for (int kf = 0; kf < 4; ++kf) {
      const int row = q0 + mi * 16 + l15;
      afr[mi][kf] = *(const short8*)(qw + (bh * SS + row) * KP + kf * 32 + (l4 << 3));
    }

  STAGEB(prA, 0);
  LOADB(prB, 1);
  __syncthreads();   // buf0 + s_mask visible

  const int hsh = (wid & 1) * 16;               // halfword select within u32
  const u32* sbp = s_b32 + (wid >> 1) * PLANE + (l4 << 2);
  float* ob0 = outg + (bh * SS + (size_t)(q0 + l15)) * SS + kvbase + (l4 << 2);
  float* ob1 = ob0 + (size_t)16 * SS;

#define CHUNK(c, PSTG, PLOAD) do {                                        \
    LOADK(c);                                                             \
    if ((c) + 2 < NCH) LOADB(PLOAD, (c) + 2);  /* early issue */          \
    f32x4 a00 = {0.f,0.f,0.f,0.f}, a01 = {0.f,0.f,0.f,0.f};               \
    f32x4 a10 = {0.f,0.f,0.f,0.f}, a11 = {0.f,0.f,0.f,0.f};               \
    _Pragma("unroll")                                                     \
    for (int _kf = 0; _kf < 4; ++_kf) {                                   \
      a00 = __builtin_amdgcn_mfma_f32_16x16x32_bf16(kfr[0][_kf], afr[0][_kf], a00, 0, 0, 0); \
      a10 = __builtin_amdgcn_mfma_f32_16x16x32_bf16(kfr[0][_kf], afr[1][_kf], a10, 0, 0, 0); \
      a01 = __builtin_amdgcn_mfma_f32_16x16x32_bf16(kfr[1][_kf], afr[0][_kf], a01, 0, 0, 0); \
      a11 = __builtin_amdgcn_mfma_f32_16x16x32_bf16(kfr[1][_kf], afr[1][_kf], a11, 0, 0, 0); \
    }                                                                     \
    if ((c) + 1 < NCH) STAGEB(PSTG, (c) + 1);                             \
    const u32* _sb = sbp + ((c) & 1) * BUFSTR;                            \
    _Pragma("unroll")                                                     \
    for (int _ni = 0; _ni < 2; ++_ni) {                                   \
      const u32 mword = s_mask32[(c) * 8 + _ni * 4 + l4];                 \
      const u32x4 bw0 = *(const u32x4*)(_sb + l15 * LROW + _ni * 16);     \
      const u32x4 bw1 = *(const u32x4*)(_sb + (l15 + 16) * LROW + _ni * 16); \
      const f32x4 ac0 = _ni ? a01 : a00;                                  \
      const f32x4 ac1 = _ni ? a11 : a10;                                  \
      float4 wv0, wv1;                                                    \
      _Pragma("unroll")                                                   \
      for (int _j = 0; _j < 4; ++_j) {                                    \
        const float _mz = ((mword >> (8 * _j)) & 0xFFu) ? 0.0f : 1.0f;    \
        const float _b0 = bf16_to_f((u16)(bw0[_j] >> hsh));               \
        const float _b1 = bf16_to_f((u16)(bw1[_j] >> hsh));               \
        ((float*)&wv0)[_j] = _mz * __expf(fmaf(ac0[_j], inv_scale, _b0)); \
        ((float*)&wv1)[_j] = _mz * __expf(fmaf(ac1[_j], inv_scale, _b1)); \
      }                                                                   \
      *(float4*)(ob0 + (size_t)((c) * CKV + _ni * 16)) = wv0;             \
      *(float4*)(ob1 + (size_t)((c) * CKV + _ni * 16)) = wv1;             \
    }                                                                     \
    __syncthreads();                                                      \
  } while (0)

#pragma unroll 1
  for (int cc = 0; cc < NCH; cc += 2) {
    CHUNK(cc,     prB, prA);   // even chunk: stage prB (c+1 odd), load prA (c+2 even)
    CHUNK(cc + 1, prA, prB);   // odd chunk:  stage prA,          load prB
  }
#undef CHUNK
#undef LOADK
#undef STAGEB
#undef LOADB
}

// ---------------- K2: per-row normalize (in place, L3-hot) -----------------
__global__ __launch_bounds__(256, 4) void norm_kernel(float* __restrict__ outg)
{
  const int wave = (int)threadIdx.x >> 6;
  const int lane = (int)threadIdx.x & 63;
  const size_t row = (size_t)blockIdx.x * 4 + wave;   // < NROWS
  float4* p = (float4*)(outg + row * (size_t)SS);

  float4 v[8];
  float sum = 0.0f;
#pragma unroll
  for (int j = 0; j < 8; ++j) {
    v[j] = p[j * 64 + lane];
    sum += (v[j].x + v[j].y) + (v[j].z + v[j].w);
  }
#pragma unroll
  for (int off = 32; off > 0; off >>= 1) sum += __shfl_xor(sum, off, 64);

  const float inv = (sum > 0.0f) ? (1.0f / sum) : 0.0f;
#pragma unroll
  for (int j = 0; j < 8; ++j) {
    v[j].x *= inv; v[j].y *= inv; v[j].z *= inv; v[j].w *= inv;
    p[j * 64 + lane] = v[j];
  }
}

extern "C" void kernel_launch(void* const* d_in, const int* in_sizes, int n_in,
                              void* d_out, int out_size, void* d_ws, size_t ws_size,
                              hipStream_t stream) {
  const float* qg = (const float*)d_in[0];
  const float* kg = (const float*)d_in[1];
  const float* sc = (const float*)d_in[2];
  const void*  mk = d_in[3];
  const float* bg = (const float*)d_in[4];
  float* out = (float*)d_out;

  // workspace: qw 8MB | kw 8MB | maskc 4KB
  u16* qw  = (u16*)d_ws;
  u16* kw  = qw + (size_t)NROWS * KP;
  u8*  mcw = (u8*)(kw + (size_t)NROWS * KP);

  mask_canon<<<dim3(1), dim3(256), 0, stream>>>(mk, mcw);
  convert_kernel<<<dim3((NROWS * (DD / 4)) / 256), dim3(256), 0, stream>>>(qg, kg, qw, kw);

  const int g1 = BB * (SS / QT) * KSPLIT;  // 1024 WGs
  score_kernel<<<dim3(g1), dim3(512), 0, stream>>>(qw, kw, sc, mcw, bg, out);

  norm_kernel<<<dim3(NROWS / 4), dim3(256), 0, stream>>>(out);
}